// Round 2
// baseline (94.682 us; speedup 1.0000x reference)
//
#include <hip/hip_runtime.h>

// ScatteringMapping closed form, single-pass (each output byte written once):
//   out[t,r,c] = U3[r,i2]*U2[i2,i1]*U1[i1,i0]*U0[i0,c] * g^tb
//   where tb = t - mL[r] - mR[c] must decompose as tb = s1[i0] + 96*i1 + 3072*i2
//   (s2 = 96*i1 and s3 = 3072*i2 exactly; s1 values are distinct in [0,96)).
//   Non-decomposable elements are zero. g = 0.9999.

#define NN 32
#define LN_G -1.0000500033334732e-4f  // ln(0.9999)

__device__ __forceinline__ float tap_val(int tb, int r, int c,
                                         const float* __restrict__ sU,
                                         const int* __restrict__ inv) {
    if (tb < 0) return 0.0f;
    unsigned ut = (unsigned)tb;
    unsigned i2 = ut / 3072u;
    if (i2 >= 32u) return 0.0f;
    unsigned rem = ut - i2 * 3072u;
    unsigned i1 = rem / 96u;          // < 32 by construction
    unsigned rem2 = rem - i1 * 96u;
    int i0 = inv[rem2];
    if (i0 < 0) return 0.0f;
    float gain = __expf((float)tb * LN_G);
    float f = sU[1 * NN * NN + i1 * NN + i0]   // U1[i1,i0]
            * sU[2 * NN * NN + i2 * NN + i1]   // U2[i2,i1]
            * sU[3 * NN * NN + r * NN + i2]    // U3[r,i2]
            * gain;
    return f * sU[i0 * NN + c];                // U0[i0,c]
}

__global__ __launch_bounds__(256) void scatter_fused_kernel(
    const float* __restrict__ U,       // (4,32,32)
    const int*   __restrict__ shifts,  // (3,32)
    const int*   __restrict__ mL,      // (32,)
    const int*   __restrict__ mR,      // (32,)
    float*       __restrict__ out,     // (T,32,32)
    int T)
{
    __shared__ float sU[4 * NN * NN];
    __shared__ int inv[96];
    __shared__ int smL[NN], smR[NN];

    const int tid = threadIdx.x;
    if (tid < 96) inv[tid] = -1;
    __syncthreads();
    if (tid < NN) {
        int s1 = shifts[tid];
        if (s1 >= 0 && s1 < 96) inv[s1] = tid;
        smL[tid] = mL[tid];
        smR[tid] = mR[tid];
    }
    for (int k = tid; k < 4 * NN * NN; k += 256) sU[k] = U[k];
    __syncthreads();

    const int total4 = T * 256;                 // float4 elements in out
    const int stride = gridDim.x * 256;
    float4* __restrict__ out4 = (float4*)out;

    for (int idx = blockIdx.x * 256 + tid; idx < total4; idx += stride) {
        const int t = idx >> 8;                 // 256 float4 per (32,32) tile
        const int pos = (idx & 255) * 4;        // element offset in tile
        const int r = pos >> 5;
        const int c = pos & 31;                 // c, c+1, c+2, c+3

        const int mlr = smL[r];
        const int m0 = smR[c], m1 = smR[c + 1], m2 = smR[c + 2], m3 = smR[c + 3];

        float4 v;
        if (m0 == m1 && m1 == m2 && m2 == m3) {
            // uniform-mR fast path: one decomposition for all 4 columns
            const int tb = t - mlr - m0;
            v.x = v.y = v.z = v.w = 0.0f;
            if (tb >= 0) {
                unsigned ut = (unsigned)tb;
                unsigned i2 = ut / 3072u;
                if (i2 < 32u) {
                    unsigned rem = ut - i2 * 3072u;
                    unsigned i1 = rem / 96u;
                    unsigned rem2 = rem - i1 * 96u;
                    int i0 = inv[rem2];
                    if (i0 >= 0) {
                        float gain = __expf((float)tb * LN_G);
                        float f = sU[1 * NN * NN + i1 * NN + i0]
                                * sU[2 * NN * NN + i2 * NN + i1]
                                * sU[3 * NN * NN + r * NN + i2]
                                * gain;
                        float4 u0 = ((const float4*)(sU + i0 * NN))[c >> 2];
                        v.x = f * u0.x; v.y = f * u0.y;
                        v.z = f * u0.z; v.w = f * u0.w;
                    }
                }
            }
        } else {
            // general path: per-column decomposition
            v.x = tap_val(t - mlr - m0, r, c + 0, sU, inv);
            v.y = tap_val(t - mlr - m1, r, c + 1, sU, inv);
            v.z = tap_val(t - mlr - m2, r, c + 2, sU, inv);
            v.w = tap_val(t - mlr - m3, r, c + 3, sU, inv);
        }
        out4[idx] = v;
    }
}

extern "C" void kernel_launch(void* const* d_in, const int* in_sizes, int n_in,
                              void* d_out, int out_size, void* d_ws, size_t ws_size,
                              hipStream_t stream) {
    const float* U      = (const float*)d_in[0];  // (4,32,32) float32
    const int*   shifts = (const int*)d_in[1];    // (3,32) int32
    const int*   mL     = (const int*)d_in[2];    // (32,) int32
    const int*   mR     = (const int*)d_in[3];    // (32,) int32
    float* out = (float*)d_out;

    const int T = out_size / (NN * NN);

    scatter_fused_kernel<<<dim3(2048), dim3(256), 0, stream>>>(
        U, shifts, mL, mR, out, T);
}

// Round 4
// 89.713 us; speedup vs baseline: 1.0554x; 1.0554x over previous
//
#include <hip/hip_runtime.h>

// ScatteringMapping closed form, single-pass (each output byte written once):
//   out[t,r,c] = U3[r,i2]*U2[i2,i1]*U1[i1,i0]*U0[i0,c] * g^tb
//   where tb = t - mL[r] - mR[c] must decompose as tb = s1[i0] + 96*i1 + 3072*i2
//   (s2 = 96*i1 and s3 = 3072*i2 exactly; s1 values are distinct in [0,96)).
//   Non-decomposable elements are zero. g = 0.9999.
// R3: nontemporal stores via clang ext_vector_type (HIP float4 is a class
// type the builtin rejects).

#define NN 32
#define LN_G -1.0000500033334732e-4f  // ln(0.9999)

typedef float fx4 __attribute__((ext_vector_type(4)));

__device__ __forceinline__ float tap_val(int tb, int r, int c,
                                         const float* __restrict__ sU,
                                         const int* __restrict__ inv) {
    if (tb < 0) return 0.0f;
    unsigned ut = (unsigned)tb;
    unsigned i2 = ut / 3072u;
    if (i2 >= 32u) return 0.0f;
    unsigned rem = ut - i2 * 3072u;
    unsigned i1 = rem / 96u;          // < 32 by construction
    unsigned rem2 = rem - i1 * 96u;
    int i0 = inv[rem2];
    if (i0 < 0) return 0.0f;
    float gain = __expf((float)tb * LN_G);
    float f = sU[1 * NN * NN + i1 * NN + i0]   // U1[i1,i0]
            * sU[2 * NN * NN + i2 * NN + i1]   // U2[i2,i1]
            * sU[3 * NN * NN + r * NN + i2]    // U3[r,i2]
            * gain;
    return f * sU[i0 * NN + c];                // U0[i0,c]
}

__global__ __launch_bounds__(256) void scatter_fused_kernel(
    const float* __restrict__ U,       // (4,32,32)
    const int*   __restrict__ shifts,  // (3,32)
    const int*   __restrict__ mL,      // (32,)
    const int*   __restrict__ mR,      // (32,)
    float*       __restrict__ out,     // (T,32,32)
    int T)
{
    __shared__ float sU[4 * NN * NN];
    __shared__ int inv[96];
    __shared__ int smL[NN], smR[NN];

    const int tid = threadIdx.x;
    if (tid < 96) inv[tid] = -1;
    __syncthreads();
    if (tid < NN) {
        int s1 = shifts[tid];
        if (s1 >= 0 && s1 < 96) inv[s1] = tid;
        smL[tid] = mL[tid];
        smR[tid] = mR[tid];
    }
    for (int k = tid; k < 4 * NN * NN; k += 256) sU[k] = U[k];
    __syncthreads();

    const int total4 = T * 256;                 // float4 elements in out
    const int stride = gridDim.x * 256;
    fx4* __restrict__ out4 = (fx4*)out;

    for (int idx = blockIdx.x * 256 + tid; idx < total4; idx += stride) {
        const int t = idx >> 8;                 // 256 float4 per (32,32) tile
        const int pos = (idx & 255) * 4;        // element offset in tile
        const int r = pos >> 5;
        const int c = pos & 31;                 // c, c+1, c+2, c+3

        const int mlr = smL[r];
        const int m0 = smR[c], m1 = smR[c + 1], m2 = smR[c + 2], m3 = smR[c + 3];

        fx4 v;
        if (m0 == m1 && m1 == m2 && m2 == m3) {
            // uniform-mR fast path: one decomposition for all 4 columns
            const int tb = t - mlr - m0;
            v = (fx4)0.0f;
            if (tb >= 0) {
                unsigned ut = (unsigned)tb;
                unsigned i2 = ut / 3072u;
                if (i2 < 32u) {
                    unsigned rem = ut - i2 * 3072u;
                    unsigned i1 = rem / 96u;
                    unsigned rem2 = rem - i1 * 96u;
                    int i0 = inv[rem2];
                    if (i0 >= 0) {
                        float gain = __expf((float)tb * LN_G);
                        float f = sU[1 * NN * NN + i1 * NN + i0]
                                * sU[2 * NN * NN + i2 * NN + i1]
                                * sU[3 * NN * NN + r * NN + i2]
                                * gain;
                        const fx4 u0 = ((const fx4*)(sU + i0 * NN))[c >> 2];
                        v = f * u0;
                    }
                }
            }
        } else {
            // general path: per-column decomposition
            v.x = tap_val(t - mlr - m0, r, c + 0, sU, inv);
            v.y = tap_val(t - mlr - m1, r, c + 1, sU, inv);
            v.z = tap_val(t - mlr - m2, r, c + 2, sU, inv);
            v.w = tap_val(t - mlr - m3, r, c + 3, sU, inv);
        }
        __builtin_nontemporal_store(v, &out4[idx]);
    }
}

extern "C" void kernel_launch(void* const* d_in, const int* in_sizes, int n_in,
                              void* d_out, int out_size, void* d_ws, size_t ws_size,
                              hipStream_t stream) {
    const float* U      = (const float*)d_in[0];  // (4,32,32) float32
    const int*   shifts = (const int*)d_in[1];    // (3,32) int32
    const int*   mL     = (const int*)d_in[2];    // (32,) int32
    const int*   mR     = (const int*)d_in[3];    // (32,) int32
    float* out = (float*)d_out;

    const int T = out_size / (NN * NN);

    scatter_fused_kernel<<<dim3(2048), dim3(256), 0, stream>>>(
        U, shifts, mL, mR, out, T);
}

// Round 5
// 87.575 us; speedup vs baseline: 1.0812x; 1.0244x over previous
//
#include <hip/hip_runtime.h>

// ScatteringMapping closed form, single-pass, tile-per-wave:
//   out[t,r,c] = U3[r,i2]*U2[i2,i1]*U1[i1,i0]*U0[i0,c] * g^tb
//   where tb = t - mL[r] - mR[c] must decompose as tb = s1[i0] + 96*i1 + 3072*i2
//   (s2 = 96*i1, s3 = 3072*i2 exactly; s1 values distinct in [0,96)).
// R4: one wave per 4KB time-tile. When mL and mR are each uniform (runtime
// check; true for the bench inputs = zeros), the decomposition is wave-uniform
// and done ONCE per tile; the wave then emits 4 back-to-back 1KB NT stores.
// General non-uniform mL/mR falls back to per-element decomposition.

#define NN 32
#define LN_G -1.0000500033334732e-4f  // ln(0.9999)

typedef float fx4 __attribute__((ext_vector_type(4)));

__device__ __forceinline__ float tap_val(int tb, int r, int c,
                                         const float* __restrict__ sU,
                                         const int* __restrict__ inv) {
    if (tb < 0) return 0.0f;
    unsigned ut = (unsigned)tb;
    unsigned i2 = ut / 3072u;
    if (i2 >= 32u) return 0.0f;
    unsigned rem = ut - i2 * 3072u;
    unsigned i1 = rem / 96u;
    unsigned rem2 = rem - i1 * 96u;
    int i0 = inv[rem2];
    if (i0 < 0) return 0.0f;
    float gain = __expf((float)tb * LN_G);
    float f = sU[1 * NN * NN + i1 * NN + i0]
            * sU[2 * NN * NN + i2 * NN + i1]
            * sU[3 * NN * NN + r * NN + i2]
            * gain;
    return f * sU[i0 * NN + c];
}

__global__ __launch_bounds__(256) void scatter_tile_kernel(
    const float* __restrict__ U,       // (4,32,32)
    const int*   __restrict__ shifts,  // (3,32)
    const int*   __restrict__ mL,      // (32,)
    const int*   __restrict__ mR,      // (32,)
    float*       __restrict__ out,     // (T,32,32)
    int T)
{
    __shared__ float sU[4 * NN * NN];   // U0..U3 as-is
    __shared__ float sU3T[NN * NN];     // U3 transposed: sU3T[i2*32 + r]
    __shared__ int inv[96];
    __shared__ int smL[NN], smR[NN];
    __shared__ int sUniform, smL0, smR0;

    const int tid = threadIdx.x;
    if (tid < 96) inv[tid] = -1;
    __syncthreads();
    if (tid < NN) {
        int s1 = shifts[tid];
        if (s1 >= 0 && s1 < 96) inv[s1] = tid;
        smL[tid] = mL[tid];
        smR[tid] = mR[tid];
    }
    for (int k = tid; k < 4 * NN * NN; k += 256) sU[k] = U[k];
    for (int k = tid; k < NN * NN; k += 256) {
        // k = r*32 + i2 of U3 -> transposed slot i2*32 + r
        sU3T[(k & 31) * NN + (k >> 5)] = U[3 * NN * NN + k];
    }
    __syncthreads();
    if (tid == 0) {
        int uL = 1, uR = 1;
        int a = smL[0], b = smR[0];
        for (int i = 1; i < NN; ++i) {
            uL &= (smL[i] == a);
            uR &= (smR[i] == b);
        }
        sUniform = uL & uR;
        smL0 = a;
        smR0 = b;
    }
    __syncthreads();

    const int wave = tid >> 6;            // 4 waves/block
    const int lane = tid & 63;
    const int nwaves = gridDim.x * 4;
    const int uniform = sUniform;
    const int mL0 = smL0, mR0 = smR0;

    fx4* __restrict__ out4 = (fx4*)out;

    for (int t = blockIdx.x * 4 + wave; t < T; t += nwaves) {
        const size_t tbase = (size_t)t * 256;   // float4 index of tile start
        if (uniform) {
            // wave-uniform decomposition, once per 4KB tile
            const int tb = t - mL0 - mR0;
            int i0 = 0, i2s = 0;
            float fcom = 0.0f;
            bool tap = false;
            if (tb >= 0) {
                unsigned ut = (unsigned)tb;
                unsigned i2 = ut / 3072u;
                if (i2 < 32u) {
                    unsigned rem = ut - i2 * 3072u;
                    unsigned i1 = rem / 96u;
                    unsigned rem2 = rem - i1 * 96u;
                    int ii0 = inv[rem2];
                    if (ii0 >= 0) {
                        tap = true;
                        i0 = ii0;
                        i2s = (int)i2;
                        fcom = sU[1 * NN * NN + i1 * NN + ii0]
                             * sU[2 * NN * NN + i2 * NN + i1]
                             * __expf((float)tb * LN_G);
                    }
                }
            }
            if (tap) {
                // c = (lane&7)*4 is j-invariant: load U0 row chunk once
                const fx4 u0v = ((const fx4*)(sU + i0 * NN))[lane & 7];
                const int rl = lane >> 3;     // r = j*8 + rl
#pragma unroll
                for (int j = 0; j < 4; ++j) {
                    const float u3 = sU3T[i2s * NN + j * 8 + rl]; // stride-1 lanes
                    const fx4 v = (fcom * u3) * u0v;
                    __builtin_nontemporal_store(v, &out4[tbase + j * 64 + lane]);
                }
            } else {
                const fx4 z = (fx4)0.0f;
#pragma unroll
                for (int j = 0; j < 4; ++j)
                    __builtin_nontemporal_store(z, &out4[tbase + j * 64 + lane]);
            }
        } else {
            // general fallback: per-element decomposition
#pragma unroll
            for (int j = 0; j < 4; ++j) {
                const int pos4 = j * 64 + lane;
                const int r = pos4 >> 3;
                const int c = (pos4 & 7) * 4;
                const int mlr = smL[r];
                fx4 v;
                v.x = tap_val(t - mlr - smR[c + 0], r, c + 0, sU, inv);
                v.y = tap_val(t - mlr - smR[c + 1], r, c + 1, sU, inv);
                v.z = tap_val(t - mlr - smR[c + 2], r, c + 2, sU, inv);
                v.w = tap_val(t - mlr - smR[c + 3], r, c + 3, sU, inv);
                __builtin_nontemporal_store(v, &out4[tbase + pos4]);
            }
        }
    }
}

extern "C" void kernel_launch(void* const* d_in, const int* in_sizes, int n_in,
                              void* d_out, int out_size, void* d_ws, size_t ws_size,
                              hipStream_t stream) {
    const float* U      = (const float*)d_in[0];  // (4,32,32) float32
    const int*   shifts = (const int*)d_in[1];    // (3,32) int32
    const int*   mL     = (const int*)d_in[2];    // (32,) int32
    const int*   mR     = (const int*)d_in[3];    // (32,) int32
    float* out = (float*)d_out;

    const int T = out_size / (NN * NN);

    scatter_tile_kernel<<<dim3(2048), dim3(256), 0, stream>>>(
        U, shifts, mL, mR, out, T);
}

// Round 6
// 86.325 us; speedup vs baseline: 1.0968x; 1.0145x over previous
//
#include <hip/hip_runtime.h>

// ScatteringMapping closed form, single-pass, split into two disjoint kernels:
//   taps: t = s1[i0] + 96*i1 + 3072*i2 (+mL0+mR0), value
//         U3[r,i2]*U2[i2,i1]*U1[i1,i0]*U0[i0,c] * g^tb
//   everything else: zero.
// R6: zero kernel writes only non-tap tiles with a CONSTANT zero data register
// (no LDS / no data recompute in the store loop -> no vmcnt WAR stalls, fill-
// rate stores). Tap test = bit (tb mod 96) of a 96-bit mask of s1 values
// (valid because 96 | 3072). Tap kernel is combo-indexed, 4 combos per wave,
// stores batched for WAR slack. Non-uniform mL/mR -> general fallback in the
// zero kernel (writes all tiles), tap kernel exits.

#define NN 32
#define LN_G -1.0000500033334732e-4f  // ln(0.9999)

typedef float fx4 __attribute__((ext_vector_type(4)));

__device__ __forceinline__ float tap_val(int tb, int r, int c,
                                         const float* __restrict__ sU,
                                         const int* __restrict__ inv) {
    if (tb < 0) return 0.0f;
    unsigned ut = (unsigned)tb;
    unsigned i2 = ut / 3072u;
    if (i2 >= 32u) return 0.0f;
    unsigned rem = ut - i2 * 3072u;
    unsigned i1 = rem / 96u;
    unsigned rem2 = rem - i1 * 96u;
    int i0 = inv[rem2];
    if (i0 < 0) return 0.0f;
    float gain = __expf((float)tb * LN_G);
    float f = sU[1 * NN * NN + i1 * NN + i0]
            * sU[2 * NN * NN + i2 * NN + i1]
            * sU[3 * NN * NN + r * NN + i2]
            * gain;
    return f * sU[i0 * NN + c];
}

__global__ __launch_bounds__(256) void zero_nontap_kernel(
    const float* __restrict__ U,       // (4,32,32)
    const int*   __restrict__ shifts,  // (3,32)
    const int*   __restrict__ mL,      // (32,)
    const int*   __restrict__ mR,      // (32,)
    float*       __restrict__ out,     // (T,32,32)
    int T)
{
    __shared__ float sU[4 * NN * NN];   // staged only for non-uniform fallback
    __shared__ int inv[96];
    __shared__ int smL[NN], smR[NN];
    __shared__ unsigned smask[3];
    __shared__ int sUniform;

    const int tid = threadIdx.x;
    if (tid < 3) smask[tid] = 0u;
    if (tid < 96) inv[tid] = -1;
    __syncthreads();
    if (tid < NN) {
        int s1 = shifts[tid];
        atomicOr(&smask[(s1 >> 5) & 3], 1u << (s1 & 31));
        if (s1 >= 0 && s1 < 96) inv[s1] = tid;
        smL[tid] = mL[tid];
        smR[tid] = mR[tid];
    }
    __syncthreads();
    if (tid == 0) {
        int uL = 1, uR = 1, a = smL[0], b = smR[0];
        for (int i = 1; i < NN; ++i) { uL &= (smL[i] == a); uR &= (smR[i] == b); }
        sUniform = uL & uR;
    }
    __syncthreads();

    const int wave = tid >> 6;
    const int lane = tid & 63;
    const int nw = gridDim.x * 4;
    const int gw = blockIdx.x * 4 + wave;
    fx4* __restrict__ out4 = (fx4*)out;

    if (sUniform) {
        const unsigned m0 = smask[0], m1 = smask[1], m2 = smask[2];
        const int base = smL[0] + smR[0];
        const fx4 z = (fx4)0.0f;   // constant data regs, never rewritten
        for (int t0 = gw * 2; t0 < T; t0 += nw * 2) {
#pragma unroll
            for (int u = 0; u < 2; ++u) {
                const int t = t0 + u;
                if (t < T) {
                    const int tb = t - base;
                    bool tap = false;
                    if (tb >= 0 && tb < NN * 3072) {
                        const unsigned rem2 = (unsigned)tb % 96u;  // 96 | 3072
                        const unsigned w = rem2 >> 5;
                        const unsigned word = (w == 0) ? m0 : ((w == 1) ? m1 : m2);
                        tap = (word >> (rem2 & 31u)) & 1u;
                    }
                    if (!tap) {
                        const size_t tb4 = (size_t)t * 256;
#pragma unroll
                        for (int j = 0; j < 4; ++j)
                            __builtin_nontemporal_store(z, &out4[tb4 + j * 64 + lane]);
                    }
                }
            }
        }
    } else {
        // general fallback: stage U, write ALL tiles per-element
        for (int k = tid; k < 4 * NN * NN; k += 256) sU[k] = U[k];
        __syncthreads();
        for (int t = gw; t < T; t += nw) {
            const size_t tb4 = (size_t)t * 256;
#pragma unroll
            for (int j = 0; j < 4; ++j) {
                const int pos4 = j * 64 + lane;
                const int r = pos4 >> 3;
                const int c = (pos4 & 7) * 4;
                const int mlr = smL[r];
                fx4 v;
                v.x = tap_val(t - mlr - smR[c + 0], r, c + 0, sU, inv);
                v.y = tap_val(t - mlr - smR[c + 1], r, c + 1, sU, inv);
                v.z = tap_val(t - mlr - smR[c + 2], r, c + 2, sU, inv);
                v.w = tap_val(t - mlr - smR[c + 3], r, c + 3, sU, inv);
                __builtin_nontemporal_store(v, &out4[tb4 + pos4]);
            }
        }
    }
}

__global__ __launch_bounds__(256) void tap_kernel(
    const float* __restrict__ U,
    const int*   __restrict__ shifts,
    const int*   __restrict__ mL,
    const int*   __restrict__ mR,
    float*       __restrict__ out,
    int T)
{
    __shared__ float sU0[NN * NN];
    __shared__ float sU1[NN * NN];
    __shared__ float sU2[NN * NN];
    __shared__ float sU3T[NN * NN];   // transposed: sU3T[i2*32 + r]
    __shared__ int s1v[NN];
    __shared__ int sUniform, sBase;

    const int tid = threadIdx.x;
    if (tid < NN) s1v[tid] = shifts[tid];
    for (int k = tid; k < NN * NN; k += 256) {
        sU0[k] = U[k];
        sU1[k] = U[NN * NN + k];
        sU2[k] = U[2 * NN * NN + k];
        sU3T[(k & 31) * NN + (k >> 5)] = U[3 * NN * NN + k];
    }
    __syncthreads();
    if (tid == 0) {
        int uL = 1, uR = 1, a = mL[0], b = mR[0];
        for (int i = 1; i < NN; ++i) { uL &= (mL[i] == a); uR &= (mR[i] == b); }
        sUniform = uL & uR;
        sBase = a + b;
    }
    __syncthreads();
    if (!sUniform) return;             // zero kernel wrote everything

    const int wave = tid >> 6;
    const int lane = tid & 63;
    const int gw = blockIdx.x * 4 + wave;
    const int base = sBase;
    const int rl = lane >> 3;          // r = j*8 + rl
    const int cb = lane & 7;           // 16B column block
    fx4* __restrict__ out4 = (fx4*)out;

    const int c0 = gw * 4;             // 4 consecutive combos per wave
    if (c0 >= NN * NN * NN) return;

#pragma unroll
    for (int p = 0; p < 2; ++p) {      // 2 pairs -> >=8 stores of WAR slack
        const int cA = c0 + 2 * p, cB = cA + 1;
        const int iA0 = cA & 31, iA1 = (cA >> 5) & 31, iA2 = cA >> 10;
        const int iB0 = cB & 31, iB1 = (cB >> 5) & 31, iB2 = cB >> 10;
        const int tbA = s1v[iA0] + 96 * iA1 + 3072 * iA2;
        const int tbB = s1v[iB0] + 96 * iB1 + 3072 * iB2;
        const int tA = tbA + base, tB = tbB + base;

        const fx4 u0A = ((const fx4*)(sU0 + iA0 * NN))[cb];
        const fx4 u0B = ((const fx4*)(sU0 + iB0 * NN))[cb];
        const float fA = sU1[iA1 * NN + iA0] * sU2[iA2 * NN + iA1]
                       * __expf((float)tbA * LN_G);
        const float fB = sU1[iB1 * NN + iB0] * sU2[iB2 * NN + iB1]
                       * __expf((float)tbB * LN_G);
        const size_t baA = (size_t)tA * 256, baB = (size_t)tB * 256;

        if (tA < T) {
#pragma unroll
            for (int j = 0; j < 4; ++j) {
                const float u3 = sU3T[iA2 * NN + j * 8 + rl];
                const fx4 v = (fA * u3) * u0A;
                __builtin_nontemporal_store(v, &out4[baA + j * 64 + lane]);
            }
        }
        if (tB < T) {
#pragma unroll
            for (int j = 0; j < 4; ++j) {
                const float u3 = sU3T[iB2 * NN + j * 8 + rl];
                const fx4 v = (fB * u3) * u0B;
                __builtin_nontemporal_store(v, &out4[baB + j * 64 + lane]);
            }
        }
    }
}

extern "C" void kernel_launch(void* const* d_in, const int* in_sizes, int n_in,
                              void* d_out, int out_size, void* d_ws, size_t ws_size,
                              hipStream_t stream) {
    const float* U      = (const float*)d_in[0];  // (4,32,32) float32
    const int*   shifts = (const int*)d_in[1];    // (3,32) int32
    const int*   mL     = (const int*)d_in[2];    // (32,) int32
    const int*   mR     = (const int*)d_in[3];    // (32,) int32
    float* out = (float*)d_out;

    const int T = out_size / (NN * NN);

    zero_nontap_kernel<<<dim3(2048), dim3(256), 0, stream>>>(
        U, shifts, mL, mR, out, T);
    tap_kernel<<<dim3(2048), dim3(256), 0, stream>>>(
        U, shifts, mL, mR, out, T);
}

// Round 7
// 83.107 us; speedup vs baseline: 1.1393x; 1.0387x over previous
//
#include <hip/hip_runtime.h>

// ScatteringMapping closed form, one wave per 4KB time-tile, ZERO loops:
//   out[t,r,c] = U3[r,i2]*U2[i2,i1]*U1[i1,i0]*U0[i0,c] * g^tb
//   tb = t - mL0 - mR0 must decompose as tb = s1[i0] + 96*i1 + 3072*i2
//   (tb%96 = s1[i0] since s1 distinct in [0,96); tb/96 = i1 + 32*i2).
// R7: fill-kernel-shaped store stream. Each wave: register-only decomposition
// (ballot for s1 membership, no LDS), compute 4 fx4 values, issue 4 NT stores
// as the LAST instructions, s_endpgm. No grid-stride loop -> no vmcnt WAR
// stalls on store operands; dispatcher keeps HBM write queues fed with fresh
// waves. Non-uniform mL/mR -> per-element fallback (cold path) in same kernel.

#define NN 32
#define LN_G -1.0000500033334732e-4f  // ln(0.9999)
#define TMAX (NN * 3072)              // 98304 = max tb + 1

typedef float fx4 __attribute__((ext_vector_type(4)));

__device__ __forceinline__ float tap_val(int tb, int r, int c,
                                         const float* __restrict__ sU,
                                         const int* __restrict__ inv) {
    if (tb < 0 || tb >= TMAX) return 0.0f;
    unsigned ut = (unsigned)tb;
    unsigned i2 = ut / 3072u;
    unsigned rem = ut - i2 * 3072u;
    unsigned i1 = rem / 96u;
    unsigned rem2 = rem - i1 * 96u;
    int i0 = inv[rem2];
    if (i0 < 0) return 0.0f;
    float gain = __expf((float)tb * LN_G);
    float f = sU[1 * NN * NN + i1 * NN + i0]
            * sU[2 * NN * NN + i2 * NN + i1]
            * sU[3 * NN * NN + r * NN + i2]
            * gain;
    return f * sU[i0 * NN + c];
}

__global__ __launch_bounds__(1024) void scat_wavetile_kernel(
    const float* __restrict__ U,       // (4,32,32)
    const int*   __restrict__ shifts,  // (3,32); stage-1 row used
    const int*   __restrict__ mL,      // (32,)
    const int*   __restrict__ mR,      // (32,)
    float*       __restrict__ out,     // (T,32,32)
    int T)
{
    __shared__ int inv[96];            // fallback only
    __shared__ float sU[4 * NN * NN];  // fallback only

    const int tid  = threadIdx.x;
    const int wave = tid >> 6;
    const int lane = tid & 63;
    const int l5   = lane & 31;

    const int t = blockIdx.x * 16 + wave;

    // tiny per-wave input loads (L1-hot broadcast)
    const int s1l = shifts[l5];
    const int mll = mL[l5];
    const int mrl = mR[l5];
    const int mL0 = __shfl(mll, 0);
    const int mR0 = __shfl(mrl, 0);
    const bool uniform = __all(mll == mL0) && __all(mrl == mR0);

    fx4* __restrict__ out4 = (fx4*)out;

    if (uniform) {
        if (t >= T) return;
        const size_t tb4 = (size_t)t * 256;   // fx4 index of tile start
        const int tb = t - mL0 - mR0;
        const int rl = lane >> 3;             // r = j*8 + rl
        const int cb = lane & 7;              // 16B column block

        fx4 v0, v1, v2, v3;
        bool tap = false;
        if (tb >= 0 && tb < TMAX) {
            const int rem2 = tb % 96;                       // = s1[i0] if tap
            const unsigned long long bal = __ballot(s1l == rem2);
            if (bal) {
                tap = true;
                const int i0 = __ffsll((long long)bal) - 1; // < 32 (lanes paired)
                const int q  = tb / 96;                     // i1 + 32*i2, <= 1023
                const int i1 = q & 31;
                const int i2 = q >> 5;
                const float fcom = U[1 * NN * NN + i1 * NN + i0]
                                 * U[2 * NN * NN + i2 * NN + i1]
                                 * __expf((float)tb * LN_G);
                const fx4 u0v = ((const fx4*)(U + i0 * NN))[cb];
                const float u30 = U[3 * NN * NN + (0 * 8 + rl) * NN + i2];
                const float u31 = U[3 * NN * NN + (1 * 8 + rl) * NN + i2];
                const float u32_ = U[3 * NN * NN + (2 * 8 + rl) * NN + i2];
                const float u33 = U[3 * NN * NN + (3 * 8 + rl) * NN + i2];
                v0 = (fcom * u30) * u0v;
                v1 = (fcom * u31) * u0v;
                v2 = (fcom * u32_) * u0v;
                v3 = (fcom * u33) * u0v;
            }
        }
        if (!tap) { v0 = v1 = v2 = v3 = (fx4)0.0f; }
        // last instructions of the wave: 4 back-to-back 1KB NT stores
        __builtin_nontemporal_store(v0, &out4[tb4 + 0 * 64 + lane]);
        __builtin_nontemporal_store(v1, &out4[tb4 + 1 * 64 + lane]);
        __builtin_nontemporal_store(v2, &out4[tb4 + 2 * 64 + lane]);
        __builtin_nontemporal_store(v3, &out4[tb4 + 3 * 64 + lane]);
        return;
    }

    // ---- non-uniform mL/mR fallback (cold path; block-uniform branch) ----
    if (tid < 96) inv[tid] = -1;
    __syncthreads();
    if (tid < 32 && s1l >= 0 && s1l < 96) inv[s1l] = tid;  // s1l = shifts[tid]
    for (int k = tid; k < 4 * NN * NN; k += 1024) sU[k] = U[k];
    __syncthreads();
    if (t >= T) return;

    const size_t tb4 = (size_t)t * 256;
#pragma unroll
    for (int j = 0; j < 4; ++j) {
        const int pos4 = j * 64 + lane;
        const int r = pos4 >> 3;
        const int c = (pos4 & 7) * 4;
        const int mlr = __shfl(mll, r);
        fx4 v;
        v.x = tap_val(t - mlr - __shfl(mrl, c + 0), r, c + 0, sU, inv);
        v.y = tap_val(t - mlr - __shfl(mrl, c + 1), r, c + 1, sU, inv);
        v.z = tap_val(t - mlr - __shfl(mrl, c + 2), r, c + 2, sU, inv);
        v.w = tap_val(t - mlr - __shfl(mrl, c + 3), r, c + 3, sU, inv);
        __builtin_nontemporal_store(v, &out4[tb4 + pos4]);
    }
}

extern "C" void kernel_launch(void* const* d_in, const int* in_sizes, int n_in,
                              void* d_out, int out_size, void* d_ws, size_t ws_size,
                              hipStream_t stream) {
    const float* U      = (const float*)d_in[0];  // (4,32,32) float32
    const int*   shifts = (const int*)d_in[1];    // (3,32) int32
    const int*   mL     = (const int*)d_in[2];    // (32,) int32
    const int*   mR     = (const int*)d_in[3];    // (32,) int32
    float* out = (float*)d_out;

    const int T = out_size / (NN * NN);           // 98304
    const int blocks = (T + 15) / 16;             // one wave per tile, 16 waves/block

    scat_wavetile_kernel<<<dim3(blocks), dim3(1024), 0, stream>>>(
        U, shifts, mL, mR, out, T);
}

// Round 8
// 77.832 us; speedup vs baseline: 1.2165x; 1.0678x over previous
//
#include <hip/hip_runtime.h>

// ScatteringMapping closed form, one wave per 4KB time-tile, ZERO loops:
//   out[t,r,c] = U3[r,i2]*U2[i2,i1]*U1[i1,i0]*U0[i0,c] * g^tb
//   tb = t - mL0 - mR0 must decompose as tb = s1[i0] + 96*i1 + 3072*i2
//   (tb%96 = s1[i0] since s1 distinct in [0,96); tb/96 = i1 + 32*i2).
// R8: A/B vs R7 — regular stores instead of nontemporal (single variable).
// Tests whether the L2 write-back path (what rocclr's 6.9 TB/s fill uses)
// beats the NT direct-to-HBM path for computed stores.

#define NN 32
#define LN_G -1.0000500033334732e-4f  // ln(0.9999)
#define TMAX (NN * 3072)              // 98304 = max tb + 1

typedef float fx4 __attribute__((ext_vector_type(4)));

__device__ __forceinline__ float tap_val(int tb, int r, int c,
                                         const float* __restrict__ sU,
                                         const int* __restrict__ inv) {
    if (tb < 0 || tb >= TMAX) return 0.0f;
    unsigned ut = (unsigned)tb;
    unsigned i2 = ut / 3072u;
    unsigned rem = ut - i2 * 3072u;
    unsigned i1 = rem / 96u;
    unsigned rem2 = rem - i1 * 96u;
    int i0 = inv[rem2];
    if (i0 < 0) return 0.0f;
    float gain = __expf((float)tb * LN_G);
    float f = sU[1 * NN * NN + i1 * NN + i0]
            * sU[2 * NN * NN + i2 * NN + i1]
            * sU[3 * NN * NN + r * NN + i2]
            * gain;
    return f * sU[i0 * NN + c];
}

__global__ __launch_bounds__(1024) void scat_wavetile_kernel(
    const float* __restrict__ U,       // (4,32,32)
    const int*   __restrict__ shifts,  // (3,32); stage-1 row used
    const int*   __restrict__ mL,      // (32,)
    const int*   __restrict__ mR,      // (32,)
    float*       __restrict__ out,     // (T,32,32)
    int T)
{
    __shared__ int inv[96];            // fallback only
    __shared__ float sU[4 * NN * NN];  // fallback only

    const int tid  = threadIdx.x;
    const int wave = tid >> 6;
    const int lane = tid & 63;
    const int l5   = lane & 31;

    const int t = blockIdx.x * 16 + wave;

    // tiny per-wave input loads (L1-hot broadcast)
    const int s1l = shifts[l5];
    const int mll = mL[l5];
    const int mrl = mR[l5];
    const int mL0 = __shfl(mll, 0);
    const int mR0 = __shfl(mrl, 0);
    const bool uniform = __all(mll == mL0) && __all(mrl == mR0);

    fx4* __restrict__ out4 = (fx4*)out;

    if (uniform) {
        if (t >= T) return;
        const size_t tb4 = (size_t)t * 256;   // fx4 index of tile start
        const int tb = t - mL0 - mR0;
        const int rl = lane >> 3;             // r = j*8 + rl
        const int cb = lane & 7;              // 16B column block

        fx4 v0, v1, v2, v3;
        bool tap = false;
        if (tb >= 0 && tb < TMAX) {
            const int rem2 = tb % 96;                       // = s1[i0] if tap
            const unsigned long long bal = __ballot(s1l == rem2);
            if (bal) {
                tap = true;
                const int i0 = __ffsll((long long)bal) - 1; // < 32 (lanes paired)
                const int q  = tb / 96;                     // i1 + 32*i2, <= 1023
                const int i1 = q & 31;
                const int i2 = q >> 5;
                const float fcom = U[1 * NN * NN + i1 * NN + i0]
                                 * U[2 * NN * NN + i2 * NN + i1]
                                 * __expf((float)tb * LN_G);
                const fx4 u0v = ((const fx4*)(U + i0 * NN))[cb];
                const float u30 = U[3 * NN * NN + (0 * 8 + rl) * NN + i2];
                const float u31 = U[3 * NN * NN + (1 * 8 + rl) * NN + i2];
                const float u32_ = U[3 * NN * NN + (2 * 8 + rl) * NN + i2];
                const float u33 = U[3 * NN * NN + (3 * 8 + rl) * NN + i2];
                v0 = (fcom * u30) * u0v;
                v1 = (fcom * u31) * u0v;
                v2 = (fcom * u32_) * u0v;
                v3 = (fcom * u33) * u0v;
            }
        }
        if (!tap) { v0 = v1 = v2 = v3 = (fx4)0.0f; }
        // last instructions of the wave: 4 back-to-back 1KB stores (regular)
        out4[tb4 + 0 * 64 + lane] = v0;
        out4[tb4 + 1 * 64 + lane] = v1;
        out4[tb4 + 2 * 64 + lane] = v2;
        out4[tb4 + 3 * 64 + lane] = v3;
        return;
    }

    // ---- non-uniform mL/mR fallback (cold path; block-uniform branch) ----
    if (tid < 96) inv[tid] = -1;
    __syncthreads();
    if (tid < 32 && s1l >= 0 && s1l < 96) inv[s1l] = tid;  // s1l = shifts[tid]
    for (int k = tid; k < 4 * NN * NN; k += 1024) sU[k] = U[k];
    __syncthreads();
    if (t >= T) return;

    const size_t tb4 = (size_t)t * 256;
#pragma unroll
    for (int j = 0; j < 4; ++j) {
        const int pos4 = j * 64 + lane;
        const int r = pos4 >> 3;
        const int c = (pos4 & 7) * 4;
        const int mlr = __shfl(mll, r);
        fx4 v;
        v.x = tap_val(t - mlr - __shfl(mrl, c + 0), r, c + 0, sU, inv);
        v.y = tap_val(t - mlr - __shfl(mrl, c + 1), r, c + 1, sU, inv);
        v.z = tap_val(t - mlr - __shfl(mrl, c + 2), r, c + 2, sU, inv);
        v.w = tap_val(t - mlr - __shfl(mrl, c + 3), r, c + 3, sU, inv);
        out4[tb4 + pos4] = v;
    }
}

extern "C" void kernel_launch(void* const* d_in, const int* in_sizes, int n_in,
                              void* d_out, int out_size, void* d_ws, size_t ws_size,
                              hipStream_t stream) {
    const float* U      = (const float*)d_in[0];  // (4,32,32) float32
    const int*   shifts = (const int*)d_in[1];    // (3,32) int32
    const int*   mL     = (const int*)d_in[2];    // (32,) int32
    const int*   mR     = (const int*)d_in[3];    // (32,) int32
    float* out = (float*)d_out;

    const int T = out_size / (NN * NN);           // 98304
    const int blocks = (T + 15) / 16;             // one wave per tile, 16 waves/block

    scat_wavetile_kernel<<<dim3(blocks), dim3(1024), 0, stream>>>(
        U, shifts, mL, mR, out, T);
}